// Round 4
// baseline (1617.752 us; speedup 1.0000x reference)
//
#include <hip/hip_runtime.h>
#include <stdint.h>

#define FEAT_IN 128
#define F1 32
#define F2 64
#define FJ 96
#define FH 128

#define BSH 8                  // 256 nodes per bucket
#define BNODES 256
#define NBMAX 512              // supports up to 512 buckets
#define CH 8192                // edges per scatter block
#define SRCBITS 17             // nN must be < 2^17 (100000 ok)

// ---------- bucket histogram ----------
__global__ void histA(const int* __restrict__ dst, int* __restrict__ bcnt, int nE, int nB) {
    __shared__ int h[NBMAX];
    for (int t = threadIdx.x; t < nB; t += blockDim.x) h[t] = 0;
    __syncthreads();
    int stride = gridDim.x * blockDim.x;
    for (int e = blockIdx.x * blockDim.x + threadIdx.x; e < nE; e += stride)
        atomicAdd(&h[dst[e] >> BSH], 1);
    __syncthreads();
    for (int t = threadIdx.x; t < nB; t += blockDim.x)
        if (h[t]) atomicAdd(&bcnt[t], h[t]);
}

// ---------- scan buckets (single block, handles nB<=1024) ----------
__global__ void scanBk(const int* __restrict__ bcnt, int* __restrict__ boff,
                       int* __restrict__ bcur, int nB, int nE) {
    __shared__ int ps[256];
    int t = threadIdx.x;
    int c[4]; int s = 0;
#pragma unroll
    for (int k = 0; k < 4; ++k) { int b = t * 4 + k; c[k] = (b < nB) ? bcnt[b] : 0; s += c[k]; }
    ps[t] = s; __syncthreads();
    for (int off = 1; off < 256; off <<= 1) {
        int v = (t >= off) ? ps[t - off] : 0; __syncthreads();
        ps[t] += v; __syncthreads();
    }
    int excl = ps[t] - s;
#pragma unroll
    for (int k = 0; k < 4; ++k) {
        int b = t * 4 + k;
        if (b < nB) { boff[b] = excl; bcur[b] = excl; excl += c[k]; }
    }
    if (t == 255) boff[nB] = nE;
}

// ---------- scatter edges into buckets, LDS-staged for coalesced writes ----------
__global__ void scatterEB(const int* __restrict__ src, const int* __restrict__ dst,
                          int* __restrict__ bcur, unsigned* __restrict__ EB, int nE, int nB) {
    __shared__ int h[NBMAX], loff[NBMAX], gbase[NBMAX], lcur[NBMAX];
    __shared__ int ps[256];
    __shared__ uint2 stage[CH];
    int t = threadIdx.x;
    int e0 = blockIdx.x * CH;
    int ecnt = min(CH, nE - e0);
    if (ecnt <= 0) return;
    for (int i = t; i < nB; i += 256) h[i] = 0;
    __syncthreads();
    for (int i = t; i < ecnt; i += 256) atomicAdd(&h[dst[e0 + i] >> BSH], 1);
    __syncthreads();
    // pair-scan over nB (<=512)
    int b0 = 2 * t, b1 = 2 * t + 1;
    int c0 = (b0 < nB) ? h[b0] : 0;
    int c1 = (b1 < nB) ? h[b1] : 0;
    ps[t] = c0 + c1; __syncthreads();
    for (int off = 1; off < 256; off <<= 1) {
        int v = (t >= off) ? ps[t - off] : 0; __syncthreads();
        ps[t] += v; __syncthreads();
    }
    int excl = ps[t] - (c0 + c1);
    if (b0 < nB) { loff[b0] = excl;      lcur[b0] = excl; }
    if (b1 < nB) { loff[b1] = excl + c0; lcur[b1] = excl + c0; }
    __syncthreads();
    for (int i = t; i < nB; i += 256)
        if (h[i]) gbase[i] = atomicAdd(&bcur[i], h[i]);
    __syncthreads();
    for (int i = t; i < ecnt; i += 256) {
        int d = dst[e0 + i], s = src[e0 + i];
        int b = d >> BSH;
        int p = atomicAdd(&lcur[b], 1);
        stage[p] = make_uint2((unsigned)s, (unsigned)d);
    }
    __syncthreads();
    for (int i = t; i < ecnt; i += 256) {
        uint2 v = stage[i];
        int bb = (int)(v.y >> BSH);
        EB[gbase[bb] + (i - loff[bb])] = v.x | ((v.y & (BNODES - 1)) << SRCBITS);
    }
}

// ---------- per-bucket degree histogram -> dinv ----------
__global__ void dinvK(const unsigned* __restrict__ EB, const int* __restrict__ boff,
                      float* __restrict__ dinv, int nN) {
    __shared__ int deg[BNODES];
    int b = blockIdx.x, t = threadIdx.x;
    deg[t] = 0;
    __syncthreads();
    int beg = boff[b], end = boff[b + 1];
    for (int i = beg + t; i < end; i += 256) atomicAdd(&deg[EB[i] >> SRCBITS], 1);
    __syncthreads();
    int node = b * BNODES + t;
    if (node < nN) dinv[node] = rsqrtf((float)deg[t] + 1.0f);
}

// ---------- g1 = (x @ W1) * dinv ----------
__global__ void gemm1_kernel(const float4* __restrict__ x4, const float* __restrict__ W1,
                             const float* __restrict__ dinv, float* __restrict__ G, int nN) {
    __shared__ float Ws[FEAT_IN * F1];
    __shared__ float xs[8][FEAT_IN];
    for (int t = threadIdx.x; t < FEAT_IN * F1; t += 256) Ws[t] = W1[t];
    int rb = blockIdx.x * 8;
    {
        int r = threadIdx.x >> 5, c = threadIdx.x & 31;
        int row = rb + r;
        float4 v = (row < nN) ? x4[(size_t)row * 32 + c] : make_float4(0, 0, 0, 0);
        ((float4*)xs[r])[c] = v;
    }
    __syncthreads();
    int r = threadIdx.x >> 5;
    int row = rb + r;
    if (row >= nN) return;
    int j = threadIdx.x & 31;
    float acc = 0.f;
#pragma unroll 8
    for (int k = 0; k < FEAT_IN; ++k) acc = fmaf(xs[r][k], Ws[k * F1 + j], acc);
    G[(size_t)row * F1 + j] = acc * dinv[row];
}

// ---------- layer-1 aggregation: LDS accumulator per bucket ----------
__global__ void __launch_bounds__(1024)
agg1B(const unsigned* __restrict__ EB, const int* __restrict__ boff,
      const float4* __restrict__ G4, const float* __restrict__ dinv,
      const float* __restrict__ b1, const int* __restrict__ batch,
      float4* __restrict__ H4, float* __restrict__ psum, int nN) {
    __shared__ float acc[BNODES * 33];   // stride 33: bank-conflict-free
    __shared__ int batchL[BNODES];
    int b = blockIdx.x, t = threadIdx.x;
    int node0 = b << BSH;
    int count = min(BNODES, nN - node0);
    for (int i = t; i < BNODES * 33; i += 1024) acc[i] = 0.f;
    if (t < count) batchL[t] = batch[node0 + t];
    __syncthreads();
    int beg = boff[b], end = boff[b + 1];
    int lane = t & 63, wv = t >> 6;
    int es = lane >> 3, comp = lane & 7;
    int e = beg + wv * 8 + es;
    for (; e + 128 < end; e += 256) {
        unsigned v0 = EB[e], v1 = EB[e + 128];
        float4 g0 = G4[((size_t)(v0 & 0x1FFFFu)) * 8 + comp];
        float4 g1 = G4[((size_t)(v1 & 0x1FFFFu)) * 8 + comp];
        int a0 = (int)(v0 >> SRCBITS) * 33 + comp * 4;
        int a1 = (int)(v1 >> SRCBITS) * 33 + comp * 4;
        atomicAdd(&acc[a0 + 0], g0.x); atomicAdd(&acc[a0 + 1], g0.y);
        atomicAdd(&acc[a0 + 2], g0.z); atomicAdd(&acc[a0 + 3], g0.w);
        atomicAdd(&acc[a1 + 0], g1.x); atomicAdd(&acc[a1 + 1], g1.y);
        atomicAdd(&acc[a1 + 2], g1.z); atomicAdd(&acc[a1 + 3], g1.w);
    }
    for (; e < end; e += 128) {
        unsigned v = EB[e];
        float4 g = G4[((size_t)(v & 0x1FFFFu)) * 8 + comp];
        int a = (int)(v >> SRCBITS) * 33 + comp * 4;
        atomicAdd(&acc[a + 0], g.x); atomicAdd(&acc[a + 1], g.y);
        atomicAdd(&acc[a + 2], g.z); atomicAdd(&acc[a + 3], g.w);
    }
    __syncthreads();
    // finalize: x1 = relu(dinv*(acc+self)+b1); H = dinv*x1; x1 back into acc
    {
        int tn = t & 255, q = t >> 8;          // q=0..3 -> feats q*8..q*8+7
        if (tn < count) {
            int node = node0 + tn;
            float dv = dinv[node];
            const float* Gp = (const float*)G4;
            float x1v[8];
#pragma unroll
            for (int i = 0; i < 8; ++i) {
                int c = q * 8 + i;
                float a = acc[tn * 33 + c] + Gp[(size_t)node * 32 + c];
                float vv = fmaf(dv, a, b1[c]);
                x1v[i] = vv > 0.f ? vv : 0.f;
            }
            float4 h0 = make_float4(dv * x1v[0], dv * x1v[1], dv * x1v[2], dv * x1v[3]);
            float4 h1 = make_float4(dv * x1v[4], dv * x1v[5], dv * x1v[6], dv * x1v[7]);
            H4[(size_t)node * 8 + q * 2 + 0] = h0;
            H4[(size_t)node * 8 + q * 2 + 1] = h1;
#pragma unroll
            for (int i = 0; i < 8; ++i) acc[tn * 33 + q * 8 + i] = x1v[i];
        }
    }
    __syncthreads();
    // segmented per-feature pool sums (batch sorted)
    if (t < F1) {
        float loc = 0.f; int curG = batchL[0];
        for (int n = 0; n < count; ++n) {
            int g = batchL[n];
            if (g != curG) { atomicAdd(&psum[(size_t)curG * FJ + t], loc); loc = 0.f; curG = g; }
            loc += acc[n * 33 + t];
        }
        atomicAdd(&psum[(size_t)curG * FJ + t], loc);
    }
}

// ---------- layer-2: aggregate H, fused 32->64 transform + relu + pool ----------
__global__ void __launch_bounds__(1024)
agg2B(const unsigned* __restrict__ EB, const int* __restrict__ boff,
      const float4* __restrict__ H4, const float* __restrict__ dinv,
      const float* __restrict__ W2, const float* __restrict__ b2,
      const int* __restrict__ batch, float* __restrict__ psum, int nN) {
    __shared__ float acc[BNODES * 33];
    __shared__ float W2s[F1 * F2];
    __shared__ float x2c[64 * 65];
    __shared__ int batchL[BNODES];
    int b = blockIdx.x, t = threadIdx.x;
    int node0 = b << BSH;
    int count = min(BNODES, nN - node0);
    for (int i = t; i < BNODES * 33; i += 1024) acc[i] = 0.f;
    for (int i = t; i < F1 * F2; i += 1024) W2s[i] = W2[i];
    if (t < count) batchL[t] = batch[node0 + t];
    __syncthreads();
    int beg = boff[b], end = boff[b + 1];
    int lane = t & 63, wv = t >> 6;
    int es = lane >> 3, comp = lane & 7;
    int e = beg + wv * 8 + es;
    for (; e + 128 < end; e += 256) {
        unsigned v0 = EB[e], v1 = EB[e + 128];
        float4 g0 = H4[((size_t)(v0 & 0x1FFFFu)) * 8 + comp];
        float4 g1 = H4[((size_t)(v1 & 0x1FFFFu)) * 8 + comp];
        int a0 = (int)(v0 >> SRCBITS) * 33 + comp * 4;
        int a1 = (int)(v1 >> SRCBITS) * 33 + comp * 4;
        atomicAdd(&acc[a0 + 0], g0.x); atomicAdd(&acc[a0 + 1], g0.y);
        atomicAdd(&acc[a0 + 2], g0.z); atomicAdd(&acc[a0 + 3], g0.w);
        atomicAdd(&acc[a1 + 0], g1.x); atomicAdd(&acc[a1 + 1], g1.y);
        atomicAdd(&acc[a1 + 2], g1.z); atomicAdd(&acc[a1 + 3], g1.w);
    }
    for (; e < end; e += 128) {
        unsigned v = EB[e];
        float4 g = H4[((size_t)(v & 0x1FFFFu)) * 8 + comp];
        int a = (int)(v >> SRCBITS) * 33 + comp * 4;
        atomicAdd(&acc[a + 0], g.x); atomicAdd(&acc[a + 1], g.y);
        atomicAdd(&acc[a + 2], g.z); atomicAdd(&acc[a + 3], g.w);
    }
    __syncthreads();
    // add self rows (coalesced)
    {
        const float* Hp = (const float*)H4;
        for (int i = t; i < count * 32; i += 1024) {
            int n = i >> 5, k = i & 31;
            acc[n * 33 + k] += Hp[(size_t)node0 * 32 + i];
        }
    }
    __syncthreads();
    // chunks of 64 nodes: transform + relu into x2c, then segmented pool sums
    int lane63 = t & 63, q16 = t >> 6;        // q16 0..15 -> j range q16*4
    float loc = 0.f;
    int curG = batchL[0];
    for (int c = 0; c < BNODES / 64; ++c) {
        int n = c * 64 + lane63;
        if (n < count) {
            float dv = dinv[node0 + n];
            int j0 = q16 * 4;
            float p0 = 0, p1 = 0, p2 = 0, p3 = 0;
#pragma unroll
            for (int k = 0; k < 32; ++k) {
                float a = acc[n * 33 + k];
                p0 = fmaf(a, W2s[k * F2 + j0 + 0], p0);
                p1 = fmaf(a, W2s[k * F2 + j0 + 1], p1);
                p2 = fmaf(a, W2s[k * F2 + j0 + 2], p2);
                p3 = fmaf(a, W2s[k * F2 + j0 + 3], p3);
            }
            x2c[lane63 * 65 + j0 + 0] = fmaxf(fmaf(dv, p0, b2[j0 + 0]), 0.f);
            x2c[lane63 * 65 + j0 + 1] = fmaxf(fmaf(dv, p1, b2[j0 + 1]), 0.f);
            x2c[lane63 * 65 + j0 + 2] = fmaxf(fmaf(dv, p2, b2[j0 + 2]), 0.f);
            x2c[lane63 * 65 + j0 + 3] = fmaxf(fmaf(dv, p3, b2[j0 + 3]), 0.f);
        }
        __syncthreads();
        int cc = min(64, count - c * 64);
        if (t < F2 && cc > 0) {
            for (int n2 = 0; n2 < cc; ++n2) {
                int g = batchL[c * 64 + n2];
                if (g != curG) { atomicAdd(&psum[(size_t)curG * FJ + F1 + t], loc); loc = 0.f; curG = g; }
                loc += x2c[n2 * 65 + t];
            }
        }
        __syncthreads();
    }
    if (t < F2) atomicAdd(&psum[(size_t)curG * FJ + F1 + t], loc);
}

__global__ void cnt_kernel(const int* __restrict__ batch, float* __restrict__ cnt, int nN) {
    int i = blockIdx.x * blockDim.x + threadIdx.x;
    if (i < nN) atomicAdd(&cnt[batch[i]], 1.0f);
}

__global__ void mlp_kernel(const float* __restrict__ psum, const float* __restrict__ cnt,
                           const float* __restrict__ fW1, const float* __restrict__ fb1,
                           const float* __restrict__ fW2, const float* __restrict__ fb2,
                           float* __restrict__ out) {
    __shared__ float p[FJ];
    __shared__ float red[FH];
    int g = blockIdx.x, tid = threadIdx.x;
    float c = fmaxf(cnt[g], 1.0f);
    if (tid < FJ) p[tid] = psum[g * FJ + tid] / c;
    __syncthreads();
    float acc = fb1[tid];
    for (int k = 0; k < FJ; ++k) acc = fmaf(p[k], fW1[k * FH + tid], acc);
    float h = fmaxf(acc, 0.f);
    red[tid] = h * fW2[tid];
    __syncthreads();
    for (int s = FH / 2; s > 0; s >>= 1) {
        if (tid < s) red[tid] += red[tid + s];
        __syncthreads();
    }
    if (tid == 0) out[g] = red[0] + fb2[0];
}

extern "C" void kernel_launch(void* const* d_in, const int* in_sizes, int n_in,
                              void* d_out, int out_size, void* d_ws, size_t ws_size,
                              hipStream_t stream) {
    const float* x   = (const float*)d_in[0];
    const int*   ei  = (const int*)d_in[1];
    const int*   bat = (const int*)d_in[2];
    const float* W1  = (const float*)d_in[3];
    const float* b1  = (const float*)d_in[4];
    const float* W2  = (const float*)d_in[5];
    const float* b2  = (const float*)d_in[6];
    const float* fW1 = (const float*)d_in[7];
    const float* fb1 = (const float*)d_in[8];
    const float* fW2 = (const float*)d_in[9];
    const float* fb2 = (const float*)d_in[10];
    float* out = (float*)d_out;

    int nN = in_sizes[0] / FEAT_IN;
    int nE = in_sizes[1] / 2;
    int nG = out_size;
    const int* src = ei;
    const int* dst = ei + nE;

    int nB  = (nN + BNODES - 1) >> BSH;
    int nCh = (nE + CH - 1) / CH;

    char* w = (char*)d_ws;
    auto alloc = [&](size_t bytes) { char* p = w; w += (bytes + 15) & ~(size_t)15; return p; };
    int*      bcnt = (int*)alloc(NBMAX * 4);
    int*      boff = (int*)alloc((NBMAX + 1) * 4);
    int*      bcur = (int*)alloc(NBMAX * 4);
    unsigned* EB   = (unsigned*)alloc((size_t)nE * 4);
    float*    dinv = (float*)alloc((size_t)nN * 4);
    float*    G    = (float*)alloc((size_t)nN * F1 * 4);
    float*    H    = (float*)alloc((size_t)nN * F1 * 4);
    float*    psum = (float*)alloc((size_t)nG * FJ * 4);
    float*    cnt  = (float*)alloc((size_t)nG * 4);

    hipMemsetAsync(bcnt, 0, NBMAX * 4, stream);
    hipMemsetAsync(psum, 0, (size_t)nG * FJ * 4, stream);
    hipMemsetAsync(cnt, 0, (size_t)nG * 4, stream);

    histA<<<1024, 256, 0, stream>>>(dst, bcnt, nE, nB);
    scanBk<<<1, 256, 0, stream>>>(bcnt, boff, bcur, nB, nE);
    scatterEB<<<nCh, 256, 0, stream>>>(src, dst, bcur, EB, nE, nB);
    dinvK<<<nB, 256, 0, stream>>>(EB, boff, dinv, nN);

    gemm1_kernel<<<(nN + 7) / 8, 256, 0, stream>>>((const float4*)x, W1, dinv, G, nN);
    agg1B<<<nB, 1024, 0, stream>>>(EB, boff, (const float4*)G, dinv, b1, bat,
                                   (float4*)H, psum, nN);
    agg2B<<<nB, 1024, 0, stream>>>(EB, boff, (const float4*)H, dinv, W2, b2,
                                   bat, psum, nN);

    cnt_kernel<<<(nN + 255) / 256, 256, 0, stream>>>(bat, cnt, nN);
    mlp_kernel<<<nG, FH, 0, stream>>>(psum, cnt, fW1, fb1, fW2, fb2, out);
}

// Round 5
// 527.767 us; speedup vs baseline: 3.0653x; 3.0653x over previous
//
#include <hip/hip_runtime.h>
#include <stdint.h>

#define FEAT_IN 128
#define F1 32
#define F2 64
#define FJ 96
#define FH 128

#define BSH 8                  // 256 nodes per bucket
#define BNODES 256
#define NBMAX 512              // supports up to 512 buckets (131072 nodes)
#define CH 8192                // edges per scatter block
#define SRCBITS 17             // nN must be < 2^17 (100000 ok)
#define SRCMASK 0x1FFFFu

// ---------- bucket histogram ----------
__global__ void histA(const int* __restrict__ dst, int* __restrict__ bcnt, int nE, int nB) {
    __shared__ int h[NBMAX];
    for (int t = threadIdx.x; t < nB; t += blockDim.x) h[t] = 0;
    __syncthreads();
    int stride = gridDim.x * blockDim.x;
    for (int e = blockIdx.x * blockDim.x + threadIdx.x; e < nE; e += stride)
        atomicAdd(&h[dst[e] >> BSH], 1);
    __syncthreads();
    for (int t = threadIdx.x; t < nB; t += blockDim.x)
        if (h[t]) atomicAdd(&bcnt[t], h[t]);
}

// ---------- scan buckets (single block) ----------
__global__ void scanBk(const int* __restrict__ bcnt, int* __restrict__ boff,
                       int* __restrict__ bcur, int nB, int nE) {
    __shared__ int ps[256];
    int t = threadIdx.x;
    int c[4]; int s = 0;
#pragma unroll
    for (int k = 0; k < 4; ++k) { int b = t * 4 + k; c[k] = (b < nB) ? bcnt[b] : 0; s += c[k]; }
    ps[t] = s; __syncthreads();
    for (int off = 1; off < 256; off <<= 1) {
        int v = (t >= off) ? ps[t - off] : 0; __syncthreads();
        ps[t] += v; __syncthreads();
    }
    int excl = ps[t] - s;
#pragma unroll
    for (int k = 0; k < 4; ++k) {
        int b = t * 4 + k;
        if (b < nB) { boff[b] = excl; bcur[b] = excl; excl += c[k]; }
    }
    if (t == 255) boff[nB] = nE;
}

// ---------- scatter edges into buckets, LDS-staged for coalesced writes ----------
__global__ void scatterEB(const int* __restrict__ src, const int* __restrict__ dst,
                          int* __restrict__ bcur, unsigned* __restrict__ EB, int nE, int nB) {
    __shared__ int h[NBMAX], loff[NBMAX], gbase[NBMAX], lcur[NBMAX];
    __shared__ int ps[256];
    __shared__ uint2 stage[CH];
    int t = threadIdx.x;
    int e0 = blockIdx.x * CH;
    int ecnt = min(CH, nE - e0);
    if (ecnt <= 0) return;
    for (int i = t; i < nB; i += 256) h[i] = 0;
    __syncthreads();
    for (int i = t; i < ecnt; i += 256) atomicAdd(&h[dst[e0 + i] >> BSH], 1);
    __syncthreads();
    int b0 = 2 * t, b1 = 2 * t + 1;
    int c0 = (b0 < nB) ? h[b0] : 0;
    int c1 = (b1 < nB) ? h[b1] : 0;
    ps[t] = c0 + c1; __syncthreads();
    for (int off = 1; off < 256; off <<= 1) {
        int v = (t >= off) ? ps[t - off] : 0; __syncthreads();
        ps[t] += v; __syncthreads();
    }
    int excl = ps[t] - (c0 + c1);
    if (b0 < nB) { loff[b0] = excl;      lcur[b0] = excl; }
    if (b1 < nB) { loff[b1] = excl + c0; lcur[b1] = excl + c0; }
    __syncthreads();
    for (int i = t; i < nB; i += 256)
        if (h[i]) gbase[i] = atomicAdd(&bcur[i], h[i]);
    __syncthreads();
    for (int i = t; i < ecnt; i += 256) {
        int d = dst[e0 + i], s = src[e0 + i];
        int b = d >> BSH;
        int p = atomicAdd(&lcur[b], 1);
        stage[p] = make_uint2((unsigned)s, (unsigned)d);
    }
    __syncthreads();
    for (int i = t; i < ecnt; i += 256) {
        uint2 v = stage[i];
        int bb = (int)(v.y >> BSH);
        EB[gbase[bb] + (i - loff[bb])] = v.x | ((v.y & (BNODES - 1)) << SRCBITS);
    }
}

// ---------- per-bucket counting sort -> csr, rowptr, dinv ----------
__global__ void __launch_bounds__(256)
bucketSortK(const unsigned* __restrict__ EB, const int* __restrict__ boff,
            int* __restrict__ rowptr, int* __restrict__ csr, float* __restrict__ dinv,
            int nN, int nE, int nB) {
    __shared__ int hist[BNODES];
    __shared__ int cur[BNODES];
    __shared__ int ps[256];
    int b = blockIdx.x, t = threadIdx.x;
    int beg = boff[b], end = boff[b + 1];
    hist[t] = 0;
    __syncthreads();
    for (int i = beg + t; i < end; i += 256) atomicAdd(&hist[EB[i] >> SRCBITS], 1);
    __syncthreads();
    int deg = hist[t];
    ps[t] = deg; __syncthreads();
    for (int off = 1; off < 256; off <<= 1) {
        int v = (t >= off) ? ps[t - off] : 0; __syncthreads();
        ps[t] += v; __syncthreads();
    }
    int excl = beg + ps[t] - deg;
    int node = (b << BSH) + t;
    if (node < nN) {
        rowptr[node] = excl;
        dinv[node] = rsqrtf((float)deg + 1.0f);
    }
    cur[t] = excl;
    if (b == nB - 1 && t == 0) rowptr[nN] = nE;
    __syncthreads();
    for (int i = beg + t; i < end; i += 256) {
        unsigned v = EB[i];
        int p = atomicAdd(&cur[v >> SRCBITS], 1);
        csr[p] = (int)(v & SRCMASK);
    }
}

// ---------- g1 = (x @ W1) * dinv ----------
__global__ void gemm1_kernel(const float4* __restrict__ x4, const float* __restrict__ W1,
                             const float* __restrict__ dinv, float* __restrict__ G, int nN) {
    __shared__ float Ws[FEAT_IN * F1];
    __shared__ float xs[8][FEAT_IN];
    for (int t = threadIdx.x; t < FEAT_IN * F1; t += 256) Ws[t] = W1[t];
    int rb = blockIdx.x * 8;
    {
        int r = threadIdx.x >> 5, c = threadIdx.x & 31;
        int row = rb + r;
        float4 v = (row < nN) ? x4[(size_t)row * 32 + c] : make_float4(0, 0, 0, 0);
        ((float4*)xs[r])[c] = v;
    }
    __syncthreads();
    int r = threadIdx.x >> 5;
    int row = rb + r;
    if (row >= nN) return;
    int j = threadIdx.x & 31;
    float acc = 0.f;
#pragma unroll 8
    for (int k = 0; k < FEAT_IN; ++k) acc = fmaf(xs[r][k], Ws[k * F1 + j], acc);
    G[(size_t)row * F1 + j] = acc * dinv[row];
}

// ---------- agg1: wave per node, 16 gathers in flight; fused H + pooled x1 ----------
__global__ void agg1_kernel(const int* __restrict__ rowptr, const int* __restrict__ csr,
                            const float4* __restrict__ G4, const float* __restrict__ dinv,
                            const float* __restrict__ b1, const int* __restrict__ batch,
                            float4* __restrict__ H4, float* __restrict__ psum, int nN) {
    int node = blockIdx.x * 4 + (threadIdx.x >> 6);
    if (node >= nN) return;
    int lane = threadIdx.x & 63;
    int es = lane >> 3;        // edge sub-slot 0..7
    int comp = lane & 7;       // float4 component group
    int beg = rowptr[node], end = rowptr[node + 1];
    float4 acc = make_float4(0.f, 0.f, 0.f, 0.f);
    int e = beg + es;
    for (; e + 8 < end; e += 16) {
        int s0 = csr[e], s1 = csr[e + 8];
        float4 g0 = G4[(size_t)s0 * 8 + comp];
        float4 g1 = G4[(size_t)s1 * 8 + comp];
        acc.x += g0.x + g1.x; acc.y += g0.y + g1.y;
        acc.z += g0.z + g1.z; acc.w += g0.w + g1.w;
    }
    if (e < end) {
        int s = csr[e];
        float4 g = G4[(size_t)s * 8 + comp];
        acc.x += g.x; acc.y += g.y; acc.z += g.z; acc.w += g.w;
    }
#pragma unroll
    for (int m = 8; m < 64; m <<= 1) {
        acc.x += __shfl_xor(acc.x, m);
        acc.y += __shfl_xor(acc.y, m);
        acc.z += __shfl_xor(acc.z, m);
        acc.w += __shfl_xor(acc.w, m);
    }
    float4 self = G4[(size_t)node * 8 + comp];
    acc.x += self.x; acc.y += self.y; acc.z += self.z; acc.w += self.w;
    float dv = dinv[node];
    float4 b = ((const float4*)b1)[comp];
    float4 x1;
    x1.x = fmaxf(fmaf(dv, acc.x, b.x), 0.f);
    x1.y = fmaxf(fmaf(dv, acc.y, b.y), 0.f);
    x1.z = fmaxf(fmaf(dv, acc.z, b.z), 0.f);
    x1.w = fmaxf(fmaf(dv, acc.w, b.w), 0.f);
    if (es == 0) {
        H4[(size_t)node * 8 + comp] = make_float4(dv * x1.x, dv * x1.y, dv * x1.z, dv * x1.w);
        int bg = batch[node];
        float* ps = psum + (size_t)bg * FJ + comp * 4;
        atomicAdd(ps + 0, x1.x);
        atomicAdd(ps + 1, x1.y);
        atomicAdd(ps + 2, x1.z);
        atomicAdd(ps + 3, x1.w);
    }
}

// ---------- agg2: gather H (32-dim), fused 32->64 GEMM + relu + pool ----------
__global__ void agg2_kernel(const int* __restrict__ rowptr, const int* __restrict__ csr,
                            const float4* __restrict__ H4, const float* __restrict__ dinv,
                            const float* __restrict__ W2, const float* __restrict__ b2,
                            const int* __restrict__ batch, float* __restrict__ psum, int nN) {
    __shared__ float W2s[F1 * F2];
    __shared__ float aLds[4][F1];
    for (int t = threadIdx.x; t < F1 * F2; t += blockDim.x) W2s[t] = W2[t];
    int wv = threadIdx.x >> 6;
    int node = blockIdx.x * 4 + wv;
    int lane = threadIdx.x & 63;
    bool valid = node < nN;
    int es = lane >> 3, comp = lane & 7;
    float4 acc = make_float4(0.f, 0.f, 0.f, 0.f);
    if (valid) {
        int beg = rowptr[node], end = rowptr[node + 1];
        int e = beg + es;
        for (; e + 8 < end; e += 16) {
            int s0 = csr[e], s1 = csr[e + 8];
            float4 g0 = H4[(size_t)s0 * 8 + comp];
            float4 g1 = H4[(size_t)s1 * 8 + comp];
            acc.x += g0.x + g1.x; acc.y += g0.y + g1.y;
            acc.z += g0.z + g1.z; acc.w += g0.w + g1.w;
        }
        if (e < end) {
            int s = csr[e];
            float4 g = H4[(size_t)s * 8 + comp];
            acc.x += g.x; acc.y += g.y; acc.z += g.z; acc.w += g.w;
        }
    }
#pragma unroll
    for (int m = 8; m < 64; m <<= 1) {
        acc.x += __shfl_xor(acc.x, m);
        acc.y += __shfl_xor(acc.y, m);
        acc.z += __shfl_xor(acc.z, m);
        acc.w += __shfl_xor(acc.w, m);
    }
    if (valid) {
        float4 self = H4[(size_t)node * 8 + comp];
        acc.x += self.x; acc.y += self.y; acc.z += self.z; acc.w += self.w;
        if (es == 0) ((float4*)aLds[wv])[comp] = acc;
    }
    __syncthreads();
    if (valid) {
        int j = lane;
        const float* a = aLds[wv];
        float dot = 0.f;
#pragma unroll
        for (int k = 0; k < F1; ++k) dot = fmaf(a[k], W2s[k * F2 + j], dot);
        float v = fmaf(dinv[node], dot, b2[j]);
        float x2 = fmaxf(v, 0.f);
        int bg = batch[node];
        atomicAdd(&psum[(size_t)bg * FJ + F1 + j], x2);
    }
}

__global__ void cnt_kernel(const int* __restrict__ batch, float* __restrict__ cnt, int nN) {
    int i = blockIdx.x * blockDim.x + threadIdx.x;
    if (i < nN) atomicAdd(&cnt[batch[i]], 1.0f);
}

__global__ void mlp_kernel(const float* __restrict__ psum, const float* __restrict__ cnt,
                           const float* __restrict__ fW1, const float* __restrict__ fb1,
                           const float* __restrict__ fW2, const float* __restrict__ fb2,
                           float* __restrict__ out) {
    __shared__ float p[FJ];
    __shared__ float red[FH];
    int g = blockIdx.x, tid = threadIdx.x;
    float c = fmaxf(cnt[g], 1.0f);
    if (tid < FJ) p[tid] = psum[g * FJ + tid] / c;
    __syncthreads();
    float acc = fb1[tid];
    for (int k = 0; k < FJ; ++k) acc = fmaf(p[k], fW1[k * FH + tid], acc);
    float h = fmaxf(acc, 0.f);
    red[tid] = h * fW2[tid];
    __syncthreads();
    for (int s = FH / 2; s > 0; s >>= 1) {
        if (tid < s) red[tid] += red[tid + s];
        __syncthreads();
    }
    if (tid == 0) out[g] = red[0] + fb2[0];
}

extern "C" void kernel_launch(void* const* d_in, const int* in_sizes, int n_in,
                              void* d_out, int out_size, void* d_ws, size_t ws_size,
                              hipStream_t stream) {
    const float* x   = (const float*)d_in[0];
    const int*   ei  = (const int*)d_in[1];
    const int*   bat = (const int*)d_in[2];
    const float* W1  = (const float*)d_in[3];
    const float* b1  = (const float*)d_in[4];
    const float* W2  = (const float*)d_in[5];
    const float* b2  = (const float*)d_in[6];
    const float* fW1 = (const float*)d_in[7];
    const float* fb1 = (const float*)d_in[8];
    const float* fW2 = (const float*)d_in[9];
    const float* fb2 = (const float*)d_in[10];
    float* out = (float*)d_out;

    int nN = in_sizes[0] / FEAT_IN;
    int nE = in_sizes[1] / 2;
    int nG = out_size;
    const int* src = ei;
    const int* dst = ei + nE;

    int nB  = (nN + BNODES - 1) >> BSH;
    int nCh = (nE + CH - 1) / CH;

    char* w = (char*)d_ws;
    auto alloc = [&](size_t bytes) { char* p = w; w += (bytes + 15) & ~(size_t)15; return p; };
    int*      bcnt   = (int*)alloc(NBMAX * 4);
    int*      boff   = (int*)alloc((NBMAX + 1) * 4);
    int*      bcur   = (int*)alloc(NBMAX * 4);
    unsigned* EB     = (unsigned*)alloc((size_t)nE * 4);
    int*      rowptr = (int*)alloc((size_t)(nN + 1) * 4);
    int*      csr    = (int*)alloc((size_t)nE * 4);
    float*    dinv   = (float*)alloc((size_t)nN * 4);
    float*    G      = (float*)alloc((size_t)nN * F1 * 4);
    float*    H      = (float*)alloc((size_t)nN * F1 * 4);
    float*    psum   = (float*)alloc((size_t)nG * FJ * 4);
    float*    cnt    = (float*)alloc((size_t)nG * 4);

    hipMemsetAsync(bcnt, 0, NBMAX * 4, stream);
    hipMemsetAsync(psum, 0, (size_t)nG * FJ * 4, stream);
    hipMemsetAsync(cnt, 0, (size_t)nG * 4, stream);

    // CSR build via dst-buckets
    histA<<<1024, 256, 0, stream>>>(dst, bcnt, nE, nB);
    scanBk<<<1, 256, 0, stream>>>(bcnt, boff, bcur, nB, nE);
    scatterEB<<<nCh, 256, 0, stream>>>(src, dst, bcur, EB, nE, nB);
    bucketSortK<<<nB, 256, 0, stream>>>(EB, boff, rowptr, csr, dinv, nN, nE, nB);

    // layer 1: transform -> aggregate (+pool x1, +H for layer 2)
    gemm1_kernel<<<(nN + 7) / 8, 256, 0, stream>>>((const float4*)x, W1, dinv, G, nN);
    agg1_kernel<<<(nN + 3) / 4, 256, 0, stream>>>(rowptr, csr, (const float4*)G, dinv, b1, bat,
                                                  (float4*)H, psum, nN);
    // layer 2: aggregate (32-dim) -> transform (+pool x2)
    agg2_kernel<<<(nN + 3) / 4, 256, 0, stream>>>(rowptr, csr, (const float4*)H, dinv, W2, b2,
                                                  bat, psum, nN);

    cnt_kernel<<<(nN + 255) / 256, 256, 0, stream>>>(bat, cnt, nN);
    mlp_kernel<<<nG, FH, 0, stream>>>(psum, cnt, fW1, fb1, fW2, fb2, out);
}